// Round 3
// baseline (87.689 us; speedup 1.0000x reference)
//
#include <hip/hip_runtime.h>
#include <hip/hip_bf16.h>

#define MULC 128
#define IN_DIM 1152
#define ROWS_PER_WG 64
#define NTHREADS 256

typedef __attribute__((ext_vector_type(8))) short bf16x8;
typedef __attribute__((ext_vector_type(4))) float f32x4;

// LDS (ushort units), 40960 total = exactly 80 KB -> 2 blocks/CU:
//  W1T: [v=0..127][128]  XOR-swizzled 16B granules, offset 0, size 16384
//  A:   [c=0..2][r=0..63][128] XOR-swizzled, offset 16384, plane 8192
// swizzle: element (row, u) lives at row*128 + ((u>>3) ^ (row&7))*8 + (u&7)
#define A_BASE 16384
#define A_PLANE 8192

__device__ __forceinline__ unsigned short f2bf(float f) {
    unsigned int b = __builtin_bit_cast(unsigned int, f);
    b += 0x7fffu + ((b >> 16) & 1u);   // round-to-nearest-even
    return (unsigned short)(b >> 16);
}

__global__ __launch_bounds__(NTHREADS, 2)
void nltp_kernel(const float* __restrict__ x, const float* __restrict__ W1,
                 const float* __restrict__ W2, const float* __restrict__ tpw,
                 float* __restrict__ out)
{
    __shared__ __align__(16) unsigned short lds[40960];
    const int t  = threadIdx.x;
    const int n0 = blockIdx.x * ROWS_PER_WG;
    const int l  = t & 63;
    const int w  = t >> 6;      // wave 0..3 owns rows [16w, 16w+16)
    const int g  = l >> 4;      // k-group 0..3
    const int li = l & 15;      // row-in-tile / v-in-tile

    // ---- x staging: 4 threads per row, each reads 96 CONTIGUOUS floats ----
    // whole block fetches 64 rows x 1536 B in one load burst (DRAM-friendly)
    const int r = t >> 2;       // 0..63
    const int q = t & 3;        // 0..3  -> u in [32q, 32q+32)
    const float* src = x + (size_t)(n0 + r) * IN_DIM + MULC + 96 * q;
    float4 F[24];
#pragma unroll
    for (int m = 0; m < 24; ++m) F[m] = ((const float4*)src)[m];

    // ---- W1^T staging: coalesced float4 reads, swizzled scalar LDS writes ----
#pragma unroll 4
    for (int it = 0; it < 16; ++it) {
        int idx = it * 256 + t;         // float4 index 0..4095
        int u   = idx >> 5;             // 0..127
        int v4  = idx & 31;
        float4 f = ((const float4*)W1)[idx];
        int ug = u >> 3, ur = u & 7;
#pragma unroll
        for (int e = 0; e < 4; ++e) {
            int v = 4 * v4 + e;
            lds[v * 128 + ((ug ^ (v & 7)) << 3) + ur] =
                f2bf(e == 0 ? f.x : e == 1 ? f.y : e == 2 ? f.z : f.w);
        }
    }

    // ---- x tile -> bf16 LDS (deinterleave c, swizzled b128 writes) ----
    {
        const float* Ff = (const float*)F;
        const int rh = r & 7;
#pragma unroll
        for (int c = 0; c < 3; ++c) {
#pragma unroll
            for (int j = 0; j < 4; ++j) {
                bf16x8 v;
#pragma unroll
                for (int s = 0; s < 8; ++s)
                    v[s] = (short)f2bf(Ff[24 * j + 3 * s + c]);   // u = 32q+8j+s
                int gran = (4 * q + j) ^ rh;
                *(bf16x8*)&lds[A_BASE + c * A_PLANE + r * 128 + (gran << 3)] = v;
            }
        }
    }
    __syncthreads();   // the only barrier

    // ---- compute: 4 K-steps, all from LDS ----
    f32x4 acc[3][8];
#pragma unroll
    for (int c = 0; c < 3; ++c)
#pragma unroll
        for (int nt = 0; nt < 8; ++nt)
            acc[c][nt] = (f32x4){0.f, 0.f, 0.f, 0.f};

    const int ar  = 16 * w + li;
    const int arh = ar & 7;
    const int lih = li & 7;
#pragma unroll
    for (int kc = 0; kc < 4; ++kc) {
        const int kk = kc * 4 + g;
        bf16x8 af[3];
#pragma unroll
        for (int c = 0; c < 3; ++c)
            af[c] = *(const bf16x8*)&lds[A_BASE + c * A_PLANE + ar * 128 + ((kk ^ arh) << 3)];
#pragma unroll
        for (int nt = 0; nt < 8; ++nt) {
            bf16x8 bfr = *(const bf16x8*)&lds[(nt * 16 + li) * 128 + ((kk ^ lih) << 3)];
            acc[0][nt] = __builtin_amdgcn_mfma_f32_16x16x32_bf16(af[0], bfr, acc[0][nt], 0, 0, 0);
            acc[1][nt] = __builtin_amdgcn_mfma_f32_16x16x32_bf16(af[1], bfr, acc[1][nt], 0, 0, 0);
            acc[2][nt] = __builtin_amdgcn_mfma_f32_16x16x32_bf16(af[2], bfr, acc[2][nt], 0, 0, 0);
        }
    }

    // ---- epilogue: silu + W2 contraction + 16-lane reduce + TP readout ----
    const float inv = 0.08838834764831845f;  // 1/sqrt(128)
    float w2a[8], w2b[8];
#pragma unroll
    for (int nt = 0; nt < 8; ++nt) {
        float2 p = *(const float2*)(W2 + 2 * (nt * 16 + li));
        w2a[nt] = p.x; w2b[nt] = p.y;
    }
    float pa[3][4], pb[3][4];
#pragma unroll
    for (int c = 0; c < 3; ++c)
#pragma unroll
        for (int rg = 0; rg < 4; ++rg) { pa[c][rg] = 0.f; pb[c][rg] = 0.f; }

#pragma unroll
    for (int c = 0; c < 3; ++c)
#pragma unroll
        for (int nt = 0; nt < 8; ++nt)
#pragma unroll
            for (int rg = 0; rg < 4; ++rg) {
                float y = acc[c][nt][rg] * inv;
                float s = y / (1.f + __expf(-y));   // silu
                pa[c][rg] += s * w2a[nt];
                pb[c][rg] += s * w2b[nt];
            }

#pragma unroll
    for (int c = 0; c < 3; ++c)
#pragma unroll
        for (int rg = 0; rg < 4; ++rg) {
            float va = pa[c][rg], vb = pb[c][rg];
            va += __shfl_xor(va, 1, 16); vb += __shfl_xor(vb, 1, 16);
            va += __shfl_xor(va, 2, 16); vb += __shfl_xor(vb, 2, 16);
            va += __shfl_xor(va, 4, 16); vb += __shfl_xor(vb, 4, 16);
            va += __shfl_xor(va, 8, 16); vb += __shfl_xor(vb, 8, 16);
            pa[c][rg] = va * inv;
            pb[c][rg] = vb * inv;
        }

    const float tw0 = tpw[0], tw1 = tpw[1], tw2 = tpw[2];
    const float k0 = tw0 * 0.5773502691896258f;   // 1/sqrt(3)
    const float k1 = tw1 * 0.7071067811865476f;   // sqrt(3)/sqrt(6)
    const float s2 = 0.7071067811865476f;
    const float s6 = 0.4082482904638631f;         // 1/sqrt(6)

#pragma unroll
    for (int rg = 0; rg < 4; ++rg) {
        float a_0 = pa[0][rg], a_1 = pa[1][rg], a_2 = pa[2][rg];
        float b_0 = pb[0][rg], b_1 = pb[1][rg], b_2 = pb[2][rg];
        float o0 = k0 * (a_0 * b_0 + a_1 * b_1 + a_2 * b_2);
        float o1 = k1 * (a_1 * b_2 - a_2 * b_1);
        float o2 = k1 * (a_2 * b_0 - a_0 * b_2);
        float o3 = k1 * (a_0 * b_1 - a_1 * b_0);
        float o4 = tw2 * (s2 * (a_2 * b_0 + a_0 * b_2));
        float o5 = tw2 * (s2 * (a_0 * b_1 + a_1 * b_0));
        float o6 = tw2 * (s6 * (2.f * a_1 * b_1 - a_2 * b_2 - a_0 * b_0));
        float o7 = tw2 * (s2 * (a_2 * b_1 + a_1 * b_2));
        float o8 = tw2 * (s2 * (a_2 * b_2 - a_0 * b_0));
        float o = li == 0 ? o0 : li == 1 ? o1 : li == 2 ? o2 : li == 3 ? o3 :
                  li == 4 ? o4 : li == 5 ? o5 : li == 6 ? o6 : li == 7 ? o7 : o8;
        if (li < 9) {
            int row = n0 + 16 * w + 4 * g + rg;
            out[row * 9 + li] = o;
        }
    }
}

extern "C" void kernel_launch(void* const* d_in, const int* in_sizes, int n_in,
                              void* d_out, int out_size, void* d_ws, size_t ws_size,
                              hipStream_t stream) {
    const float* x   = (const float*)d_in[0];
    const float* W1  = (const float*)d_in[1];
    const float* W2  = (const float*)d_in[2];
    const float* tpw = (const float*)d_in[3];
    float* out = (float*)d_out;
    const int n = in_sizes[0] / IN_DIM;           // 131072
    dim3 grid(n / ROWS_PER_WG);                   // 2048
    nltp_kernel<<<grid, NTHREADS, 0, stream>>>(x, W1, W2, tpw, out);
}